// Round 6
// baseline (320.827 us; speedup 1.0000x reference)
//
#include <hip/hip_runtime.h>
#include <math.h>

// ---------------------------------------------------------------------------
// Llama attention block, MI355X bf16-MFMA implementation (round 6).
//   prep: fused X-cast + all W transposes.
//   GEMM1: fused QKV + RoPE/scale/pack; V epilogue writes Vt TRANSPOSED
//          (per-wave LDS transpose, no separate kernel).
//   Flash v3 (unchanged): 2-wave blocks, paired strips.
//   GEMM2: 128m x 64n tiles -> 1024 blocks = 4/CU, 16 waves/CU.
// ---------------------------------------------------------------------------

typedef float f32x4 __attribute__((ext_vector_type(4)));
typedef short s16x8 __attribute__((ext_vector_type(8)));
typedef unsigned short u16x4 __attribute__((ext_vector_type(4)));

__device__ __forceinline__ unsigned short f2bf(float x) {
    union { float f; unsigned int u; } v; v.f = x;
    unsigned int r = v.u + 0x7FFF + ((v.u >> 16) & 1);   // RNE
    return (unsigned short)(r >> 16);
}

// --------------------- prep: cast X + transpose-cast W ---------------------
__global__ __launch_bounds__(256) void prep(
    const float* __restrict__ X, const float* __restrict__ Wq,
    const float* __restrict__ Wk, const float* __restrict__ Wv,
    const float* __restrict__ Wo,
    unsigned short* __restrict__ Xb, unsigned short* __restrict__ Wqkvt,
    unsigned short* __restrict__ Wot) {
    const int bid = blockIdx.x;
    if (bid < 8192) {                                // ---- cast X -> bf16
        size_t i = (size_t)bid * 256 + threadIdx.x;
        f32x4 v = *(const f32x4*)&X[i * 4];
        u16x4 r;
        r[0] = f2bf(v[0]); r[1] = f2bf(v[1]); r[2] = f2bf(v[2]); r[3] = f2bf(v[3]);
        *(u16x4*)&Xb[i * 4] = r;
        return;
    }
    __shared__ float t[32][33];
    const int tb = bid - 8192;                       // 0..10239
    const int kbi = tb / 160, bx = tb - kbi * 160;
    const float* W; unsigned short* Out; int N, n0, nb;
    if (bx < 64)      { W = Wq; Out = Wqkvt; N = 2048; n0 = 0;    nb = bx; }
    else if (bx < 80) { W = Wk; Out = Wqkvt; N = 512;  n0 = 2048; nb = bx - 64; }
    else if (bx < 96) { W = Wv; Out = Wqkvt; N = 512;  n0 = 2560; nb = bx - 80; }
    else              { W = Wo; Out = Wot;   N = 2048; n0 = 0;    nb = bx - 96; }
    int kb = kbi * 32; nb *= 32;
    int tx = threadIdx.x & 31, ty = threadIdx.x >> 5;
#pragma unroll
    for (int i = 0; i < 4; ++i)
        t[ty + i * 8][tx] = W[(size_t)(kb + ty + i * 8) * N + nb + tx];
    __syncthreads();
#pragma unroll
    for (int i = 0; i < 4; ++i)
        Out[(size_t)(n0 + nb + ty + i * 8) * 2048 + kb + tx] = f2bf(t[tx][ty + i * 8]);
}

// --------------- fused QKV GEMM + RoPE + pack (GEMM1) ----------------------
// M=4096, N=3072 (Q|K|V), K=2048. Q: RoPE x0.125 -> Qb. K: RoPE -> Kb.
// V: per-wave LDS transpose -> Vt [b,kvh,d,s].
__global__ __launch_bounds__(256) void gemm_qkv_rope(
    const unsigned short* __restrict__ A, const unsigned short* __restrict__ Bt,
    const int* __restrict__ pos,
    unsigned short* __restrict__ Qb, unsigned short* __restrict__ Kb,
    unsigned short* __restrict__ Vt) {
    const int K = 2048;
    __shared__ unsigned short As[128 * 64];
    __shared__ unsigned short Bs[128 * 64];
    const int tid = threadIdx.x;
    const int wave = tid >> 6, lane = tid & 63;
    const int col = lane & 15, quad = lane >> 4;
    const int m0 = blockIdx.y * 128, n0 = blockIdx.x * 128;
    const int wm = (wave >> 1) * 64, wn = (wave & 1) * 64;

    const int lrow = lane >> 3;
    const int gch = (lane & 7) ^ lrow;
    const unsigned short* Ag = A + (size_t)(m0 + wave * 32 + lrow) * K + gch * 8;
    const unsigned short* Bg = Bt + (size_t)(n0 + wave * 32 + lrow) * K + gch * 8;
    unsigned short* AsW = As + wave * 2048;
    unsigned short* BsW = Bs + wave * 2048;

    f32x4 acc[4][4] = {};

    for (int k0 = 0; k0 < K; k0 += 64) {
#pragma unroll
        for (int i = 0; i < 4; ++i) {
            __builtin_amdgcn_global_load_lds(
                (const __attribute__((address_space(1))) void*)(Ag + (size_t)i * 8 * K + k0),
                (__attribute__((address_space(3))) void*)(AsW + i * 512), 16, 0, 0);
            __builtin_amdgcn_global_load_lds(
                (const __attribute__((address_space(1))) void*)(Bg + (size_t)i * 8 * K + k0),
                (__attribute__((address_space(3))) void*)(BsW + i * 512), 16, 0, 0);
        }
        __syncthreads();
#pragma unroll
        for (int ks = 0; ks < 2; ++ks) {
            const int slot = ((ks << 2) + quad) ^ (col & 7);
            s16x8 af[4], bf[4];
#pragma unroll
            for (int mi = 0; mi < 4; ++mi)
                af[mi] = *(const s16x8*)&As[(wm + mi * 16 + col) * 64 + slot * 8];
#pragma unroll
            for (int ni = 0; ni < 4; ++ni)
                bf[ni] = *(const s16x8*)&Bs[(wn + ni * 16 + col) * 64 + slot * 8];
#pragma unroll
            for (int mi = 0; mi < 4; ++mi)
#pragma unroll
                for (int ni = 0; ni < 4; ++ni)
                    acc[mi][ni] = __builtin_amdgcn_mfma_f32_16x16x32_bf16(
                        af[mi], bf[ni], acc[mi][ni], 0, 0, 0);
        }
        __syncthreads();
    }

    const int cb = n0 + wn;
    if (cb >= 2560) {
        // ---- V: transpose 64s x 64d wave-tile via private LDS region ------
        const int hd = (cb - 2560) >> 6;             // kv head 0..7
        unsigned short* t = (wave < 2) ? (As + wave * 4096) : (Bs + (wave - 2) * 4096);
#pragma unroll
        for (int mi = 0; mi < 4; ++mi)
#pragma unroll
            for (int ni = 0; ni < 4; ++ni)
#pragma unroll
                for (int r = 0; r < 4; ++r) {
                    int sl = mi * 16 + quad * 4 + r;         // local s 0..63
                    int d  = ni * 16 + col;                  // 0..63
                    int ch = (sl >> 3) ^ (d & 7);            // chunk swizzle
                    t[d * 64 + ch * 8 + (sl & 7)] = f2bf(acc[mi][ni][r]);
                }
        asm volatile("s_waitcnt lgkmcnt(0)" ::: "memory");   // same-wave visibility
        const int b = m0 >> 11;
        const int s0 = (m0 & 2047) + wm;
        unsigned short* dst = Vt + ((size_t)(b * 8 + hd) * 64) * 2048 + s0;
        const int c = lane & 7;
#pragma unroll
        for (int it = 0; it < 8; ++it) {
            int d = it * 8 + (lane >> 3);
            int ch = c ^ (d & 7);
            s16x8 v = *(const s16x8*)&t[d * 64 + ch * 8];
            *(s16x8*)&dst[(size_t)d * 2048 + c * 8] = v;
        }
    } else {                                         // Q or K: RoPE
        const int isQ = (cb < 2048);
        const int hd = isQ ? (cb >> 6) : ((cb - 2048) >> 6);
        const int nh = isQ ? 32 : 8;
        const float scale = isQ ? 0.125f : 1.0f;
        unsigned short* Out = isQ ? Qb : Kb;
        const float NEG_LN_TH_32 = -0.28782313662425575f;
        const float inv0 = __expf((float)col * NEG_LN_TH_32);
        const float inv1 = __expf((float)(col + 16) * NEG_LN_TH_32);
#pragma unroll
        for (int mi = 0; mi < 4; ++mi)
#pragma unroll
            for (int r = 0; r < 4; ++r) {
                int m = m0 + wm + mi * 16 + quad * 4 + r;
                int b = m >> 11, s = m & 2047;
                float p = (float)pos[m];
                float sn0, cs0, sn1, cs1;
                __sincosf(p * inv0, &sn0, &cs0);
                __sincosf(p * inv1, &sn1, &cs1);
                float a0 = acc[mi][0][r], a1 = acc[mi][1][r];
                float b0 = acc[mi][2][r], b1 = acc[mi][3][r];
                size_t rb = ((size_t)(b * nh + hd) * 2048 + s) * 64;
                Out[rb + col]      = f2bf((a0 * cs0 - b0 * sn0) * scale);
                Out[rb + col + 16] = f2bf((a1 * cs1 - b1 * sn1) * scale);
                Out[rb + col + 32] = f2bf((b0 * cs0 + a0 * sn0) * scale);
                Out[rb + col + 48] = f2bf((b1 * cs1 + a1 * sn1) * scale);
            }
    }
}

// ------------------------ GEMM2: 128m x 64n tiles --------------------------
// C(4096 x 2048, f32) = A(4096 x 2048 bf16) * Bt(2048 x 2048 bf16)^T.
// 1024 blocks = 4/CU, 16 waves/CU. Wave = 64m x 32n, acc 4x2.
__global__ __launch_bounds__(256, 4) void gemm2_nt(
    const unsigned short* __restrict__ A, const unsigned short* __restrict__ Bt,
    float* __restrict__ C) {
    const int K = 2048, ldc = 2048;
    __shared__ unsigned short As[128 * 64];          // 16 KB
    __shared__ unsigned short Bs[64 * 64];           // 8 KB
    const int tid = threadIdx.x;
    const int wave = tid >> 6, lane = tid & 63;
    const int col = lane & 15, quad = lane >> 4;
    const int m0 = blockIdx.y * 128, n0 = blockIdx.x * 64;
    const int wm = (wave >> 1) * 64, wn = (wave & 1) * 32;

    const int lrow = lane >> 3;
    const int gch = (lane & 7) ^ lrow;
    const unsigned short* Ag = A + (size_t)(m0 + wave * 32 + lrow) * K + gch * 8;
    const unsigned short* Bg = Bt + (size_t)(n0 + wave * 16 + lrow) * K + gch * 8;
    unsigned short* AsW = As + wave * 2048;          // 32 rows
    unsigned short* BsW = Bs + wave * 1024;          // 16 rows

    f32x4 acc[4][2] = {};

    for (int k0 = 0; k0 < K; k0 += 64) {
#pragma unroll
        for (int i = 0; i < 4; ++i)
            __builtin_amdgcn_global_load_lds(
                (const __attribute__((address_space(1))) void*)(Ag + (size_t)i * 8 * K + k0),
                (__attribute__((address_space(3))) void*)(AsW + i * 512), 16, 0, 0);
#pragma unroll
        for (int i = 0; i < 2; ++i)
            __builtin_amdgcn_global_load_lds(
                (const __attribute__((address_space(1))) void*)(Bg + (size_t)i * 8 * K + k0),
                (__attribute__((address_space(3))) void*)(BsW + i * 512), 16, 0, 0);
        __syncthreads();
#pragma unroll
        for (int ks = 0; ks < 2; ++ks) {
            const int slot = ((ks << 2) + quad) ^ (col & 7);
            s16x8 af[4], bf[2];
#pragma unroll
            for (int mi = 0; mi < 4; ++mi)
                af[mi] = *(const s16x8*)&As[(wm + mi * 16 + col) * 64 + slot * 8];
#pragma unroll
            for (int ni = 0; ni < 2; ++ni)
                bf[ni] = *(const s16x8*)&Bs[(wn + ni * 16 + col) * 64 + slot * 8];
#pragma unroll
            for (int mi = 0; mi < 4; ++mi)
#pragma unroll
                for (int ni = 0; ni < 2; ++ni)
                    acc[mi][ni] = __builtin_amdgcn_mfma_f32_16x16x32_bf16(
                        af[mi], bf[ni], acc[mi][ni], 0, 0, 0);
        }
        __syncthreads();
    }
#pragma unroll
    for (int mi = 0; mi < 4; ++mi)
#pragma unroll
        for (int ni = 0; ni < 2; ++ni)
#pragma unroll
            for (int r = 0; r < 4; ++r) {
                int m = m0 + wm + mi * 16 + quad * 4 + r;
                int n = n0 + wn + ni * 16 + col;
                C[(size_t)m * ldc + n] = acc[mi][ni][r];
            }
}

// ---------------------------- flash attention v3 ---------------------------
__global__ __launch_bounds__(128, 2) void flash_attn(
    const unsigned short* __restrict__ Qb, const unsigned short* __restrict__ Kb,
    const unsigned short* __restrict__ Vt, unsigned short* __restrict__ Ob) {
    __shared__ unsigned short Ks[64 * 64];           // [kv][d]   xor-chunked
    __shared__ unsigned short Vs[64 * 64];           // [d][kv]   xor-chunked
    __shared__ unsigned short PsA[2][32 * 64];
    __shared__ unsigned short PsB[2][32 * 64];

    const int tid = threadIdx.x;
    const int wave = tid >> 6, lane = tid & 63;
    const int col = lane & 15, quad = lane >> 4;

    const int id = blockIdx.x;                       // 0..1023
    const int j = ((id & 15) + ((id >> 8) << 2)) & 15;
    const int bh = id >> 4;
    const int b = bh >> 5, h = bh & 31, kvh = h >> 2;
    const int qA0 = (31 - j) * 64, qB0 = j * 64;
    const int qwA = qA0 + wave * 32, qwB = qB0 + wave * 32;

    const unsigned short* Qg  = Qb + ((size_t)(b * 32 + h) * 2048) * 64;
    const unsigned short* Kgb = Kb + ((size_t)(b * 8 + kvh) * 2048) * 64;
    const unsigned short* Vgb = Vt + ((size_t)(b * 8 + kvh) * 64) * 2048;

    const int r8 = lane >> 3, g = (lane & 7) ^ r8;
    const unsigned short* KgL = Kgb + (size_t)(wave * 32 + r8) * 64 + g * 8;
    const unsigned short* VgL = Vgb + (size_t)(wave * 32 + r8) * 2048 + g * 8;
    unsigned short* KsW = Ks + wave * 32 * 64;
    unsigned short* VsW = Vs + wave * 32 * 64;

    const s16x8 onesf = {16256, 16256, 16256, 16256, 16256, 16256, 16256, 16256};

    s16x8 qfA[2][2], qfB[2][2];
#pragma unroll
    for (int qc = 0; qc < 2; ++qc)
#pragma unroll
        for (int ks = 0; ks < 2; ++ks) {
            qfA[qc][ks] = *(const s16x8*)&Qg[(size_t)(qwA + qc * 16 + col) * 64 + ks * 32 + quad * 8];
            qfB[qc][ks] = *(const s16x8*)&Qg[(size_t)(qwB + qc * 16 + col) * 64 + ks * 32 + quad * 8];
        }

    f32x4 aoA[2][4] = {}, aoB[2][4] = {};
    f32x4 alA[2] = {}, alB[2] = {};

    for (int kv0 = 0; kv0 <= qA0; kv0 += 64) {
#pragma unroll
        for (int i = 0; i < 4; ++i) {
            __builtin_amdgcn_global_load_lds(
                (const __attribute__((address_space(1))) void*)(KgL + (size_t)(kv0 + i * 8) * 64),
                (__attribute__((address_space(3))) void*)(KsW + i * 512), 16, 0, 0);
            __builtin_amdgcn_global_load_lds(
                (const __attribute__((address_space(1))) void*)(VgL + kv0 + (size_t)i * 8 * 2048),
                (__attribute__((address_space(3))) void*)(VsW + i * 512), 16, 0, 0);
        }
        __syncthreads();
        const bool doB = (kv0 <= qB0);
#pragma unroll
        for (int mi = 0; mi < 4; ++mi) {
            const int s0 = quad ^ (col & 7);
            const int s1 = (4 + quad) ^ (col & 7);
            s16x8 kf0 = *(const s16x8*)&Ks[(mi * 16 + col) * 64 + s0 * 8];
            s16x8 kf1 = *(const s16x8*)&Ks[(mi * 16 + col) * 64 + s1 * 8];
            const int chl = (mi * 2 + (quad >> 1)) ^ (col & 7);
#pragma unroll
            for (int qc = 0; qc < 2; ++qc) {
                f32x4 sc = {};
                sc = __builtin_amdgcn_mfma_f32_16x16x32_bf16(kf0, qfA[qc][0], sc, 0, 0, 0);
                sc = __builtin_amdgcn_mfma_f32_16x16x32_bf16(kf1, qfA[qc][1], sc, 0, 0, 0);
                if (kv0 == qA0) {
                    int kvb = kv0 + mi * 16 + quad * 4, q = qwA + qc * 16 + col;
#pragma unroll
                    for (int r = 0; r < 4; ++r)
                        if (kvb + r > q) sc[r] = -1e30f;
                }
                unsigned eb[4];
#pragma unroll
                for (int r = 0; r < 4; ++r) eb[r] = __float_as_uint(__expf(sc[r]));
                uint2 pk;
                pk.x = __builtin_amdgcn_perm(eb[1], eb[0], 0x07060302u);
                pk.y = __builtin_amdgcn_perm(eb[3], eb[2], 0x07060302u);
                *(uint2*)&PsA[wave][(qc * 16 + col) * 64 + chl * 8 + (quad & 1) * 4] = pk;
            }
            if (doB) {
#pragma unroll
                for (int qc = 0; qc < 2; ++qc) {
                    f32x4 sc = {};
                    sc = __builtin_amdgcn_mfma_f32_16x16x32_bf16(kf0, qfB[qc][0], sc, 0, 0, 0);
                    sc = __builtin_amdgcn_mfma_f32_16x16x32_bf16(kf1, qfB[qc][1], sc, 0, 0, 0);
                    if (kv0 == qB0) {
                        int kvb = kv0 + mi * 16 + quad * 4, q = qwB + qc * 16 + col;
#pragma unroll
                        for (int r = 0; r < 4; ++r)
                            if (kvb + r > q) sc[r] = -1e30f;
                    }
                    unsigned eb[4];
#pragma unroll
                    for (int r = 0; r < 4; ++r) eb[r] = __float_as_uint(__expf(sc[r]));
                    uint2 pk;
                    pk.x = __builtin_amdgcn_perm(eb[1], eb[0], 0x07060302u);
                    pk.y = __builtin_amdgcn_perm(eb[3], eb[2], 0x07060302u);
                    *(uint2*)&PsB[wave][(qc * 16 + col) * 64 + chl * 8 + (quad & 1) * 4] = pk;
                }
            }
        }
        asm volatile("s_waitcnt lgkmcnt(0)" ::: "memory");
#pragma unroll
        for (int ks = 0; ks < 2; ++ks) {
            const int slot = ((ks << 2) + quad) ^ (col & 7);
            s16x8 vf[4];
#pragma unroll
            for (int di = 0; di < 4; ++di)
                vf[di] = *(const s16x8*)&Vs[(di * 16 + col) * 64 + slot * 8];
#pragma unroll
            for (int qc = 0; qc < 2; ++qc) {
                s16x8 pfA = *(const s16x8*)&PsA[wave][(qc * 16 + col) * 64 + slot * 8];
                alA[qc] = __builtin_amdgcn_mfma_f32_16x16x32_bf16(pfA, onesf, alA[qc], 0, 0, 0);
#pragma unroll
                for (int di = 0; di < 4; ++di)
                    aoA[qc][di] = __builtin_amdgcn_mfma_f32_16x16x32_bf16(pfA, vf[di], aoA[qc][di], 0, 0, 0);
            }
            if (doB) {
#pragma unroll
                for (int qc = 0; qc < 2; ++qc) {
                    s16x8 pfB = *(const s16x8*)&PsB[wave][(qc * 16 + col) * 64 + slot * 8];
                    alB[qc] = __builtin_amdgcn_mfma_f32_16x16x32_bf16(pfB, onesf, alB[qc], 0, 0, 0);
#pragma unroll
                    for (int di = 0; di < 4; ++di)
                        aoB[qc][di] = __builtin_amdgcn_mfma_f32_16x16x32_bf16(pfB, vf[di], aoB[qc][di], 0, 0, 0);
                }
            }
        }
        __syncthreads();
    }

#pragma unroll
    for (int qc = 0; qc < 2; ++qc)
#pragma unroll
        for (int r = 0; r < 4; ++r) {
            {
                int qg = qwA + qc * 16 + quad * 4 + r;
                float inv = 1.f / alA[qc][r];
                size_t base = ((size_t)b * 2048 + qg) * 2048 + h * 64;
#pragma unroll
                for (int di = 0; di < 4; ++di)
                    Ob[base + di * 16 + col] = f2bf(aoA[qc][di][r] * inv);
            }
            {
                int qg = qwB + qc * 16 + quad * 4 + r;
                float inv = 1.f / alB[qc][r];
                size_t base = ((size_t)b * 2048 + qg) * 2048 + h * 64;
#pragma unroll
                for (int di = 0; di < 4; ++di)
                    Ob[base + di * 16 + col] = f2bf(aoB[qc][di][r] * inv);
            }
        }
}

// ------------------------------- launcher ----------------------------------
extern "C" void kernel_launch(void* const* d_in, const int* in_sizes, int n_in,
                              void* d_out, int out_size, void* d_ws, size_t ws_size,
                              hipStream_t stream) {
    const float* X  = (const float*)d_in[0];
    const float* Wq = (const float*)d_in[1];
    const float* Wk = (const float*)d_in[2];
    const float* Wv = (const float*)d_in[3];
    const float* Wo = (const float*)d_in[4];
    const int* pos  = (const int*)d_in[6];
    float* out = (float*)d_out;

    char* ws = (char*)d_ws;
    unsigned short* Xb    = (unsigned short*)(ws + 0);          // 16 MB (reused as Attn)
    unsigned short* Wqkvt = (unsigned short*)(ws + 16777216);   // 12 MB
    unsigned short* Wot   = (unsigned short*)(ws + 29360128);   // 8 MB
    unsigned short* Qb    = (unsigned short*)(ws + 37748736);   // 16 MB
    unsigned short* Kb    = (unsigned short*)(ws + 54525952);   // 4 MB
    unsigned short* Vt    = (unsigned short*)(ws + 58720256);   // 4 MB
    unsigned short* Attn  = Xb;                                 // alias

    prep<<<18432, 256, 0, stream>>>(X, Wq, Wk, Wv, Wo, Xb, Wqkvt, Wot);
    gemm_qkv_rope<<<dim3(24, 32), 256, 0, stream>>>(Xb, Wqkvt, pos, Qb, Kb, Vt);
    flash_attn<<<1024, 128, 0, stream>>>(Qb, Kb, Vt, Attn);
    gemm2_nt<<<dim3(32, 32), 256, 0, stream>>>(Attn, Wot, out);
}